// Round 2
// baseline (95.136 us; speedup 1.0000x reference)
//
#include <hip/hip_runtime.h>
#include <cfloat>

// Problem dims (fixed by reference)
#define BB   256   // batch
#define DIM  512
#define NN   196
#define TB   8     // b-tile in prep kernel
#define KT   64    // k-tile (d) in prep kernel

// ---------------------------------------------------------------------------
// Kernel 1: prep — w[b,i] = (mem[b,i] + b_mem[i]) * v1[b,i] + v2[b,i]
//   mem[b,i] = sum_d memory[-1][b,d] * W_mem[d,i]
//   v1[b,i]  = sum_d u[b,d] * W_concat[i,     d]   (u = control[-1]*W_attn)
//   v2[b,i]  = sum_d u[b,d] * W_concat[DIM+i, d]
// grid (BB/TB, DIM/64) = (32, 8) x 256 threads. Per 2-dd step:
//   1 lane ds_read_b128 (c1,c2,c1',c2') + 2 broadcast b128 (m,u pairs)
//   + 2 global b32 (W_mem col) + 12 FMA  -> VALU-bound (~2.6us floor).
// ---------------------------------------------------------------------------
__global__ __launch_bounds__(256) void prep_kernel(
    const float* __restrict__ memory,    // (2,BB,DIM)
    const float* __restrict__ control,   // (2,BB,DIM)
    const float* __restrict__ W_mem,     // (DIM,DIM) row-major [d][i]
    const float* __restrict__ b_mem,     // (DIM)
    const float* __restrict__ W_concat,  // (2*DIM, DIM) row-major [c][j]
    const float* __restrict__ W_attn,    // (DIM,1)
    float* __restrict__ w_out)           // (BB, DIM)
{
    __shared__ float2 MU[TB][66];        // (m,u) slice for current k-tile
    __shared__ float4 WT[KT / 2][67];    // (c1,c2 | dd) , (c1,c2 | dd+1) per il

    const int tid = threadIdx.x;
    const int b0 = blockIdx.x * TB;
    const int i0 = blockIdx.y * 64;

    const float* mem_in = memory  + (size_t)BB * DIM;  // memory[-1]
    const float* ctl_in = control + (size_t)BB * DIM;  // control[-1]

    const int il   = tid & 63;      // i within tile
    const int slot = tid >> 6;      // 0..3 ; handles b-rows slot and slot+4
    const int i    = i0 + il;

    // W-tile staging coords: 64 rows x 16 cols per pass, 4 passes
    const int sr = tid >> 2;        // 0..63 (row = i_local)
    const int sc = (tid & 3) * 4;   // float4 col within 16-col pass

    float am0 = 0.f, am1 = 0.f;     // mem accumulators
    float a10 = 0.f, a11 = 0.f;     // v1
    float a20 = 0.f, a21 = 0.f;     // v2

    for (int kt = 0; kt < DIM; kt += KT) {
        __syncthreads();  // previous tile's compute done

        // stage MU slice: 8 b-rows x 64 d, 512 float2 by 256 threads
        {
            int idx = tid;
            #pragma unroll
            for (int p = 0; p < 2; ++p, idx += 256) {
                const int bb = idx >> 6, dl = idx & 63;
                const float mv = mem_in[(size_t)(b0 + bb) * DIM + kt + dl];
                const float uv = ctl_in[(size_t)(b0 + bb) * DIM + kt + dl] * W_attn[kt + dl];
                MU[bb][dl] = make_float2(mv, uv);
            }
        }
        // stage W_concat tiles (rows i0.., DIM+i0.., cols kt..kt+63), interleaved
        #pragma unroll
        for (int cc = 0; cc < KT; cc += 16) {
            const float4 q1 = *(const float4*)&W_concat[(size_t)(i0 + sr) * DIM + kt + cc + sc];
            const float4 q2 = *(const float4*)&W_concat[(size_t)(DIM + i0 + sr) * DIM + kt + cc + sc];
            const int dd2 = (cc + sc) >> 1;
            WT[dd2][sr]     = make_float4(q1.x, q2.x, q1.y, q2.y);
            WT[dd2 + 1][sr] = make_float4(q1.z, q2.z, q1.w, q2.w);
        }
        __syncthreads();

        #pragma unroll 8
        for (int dd = 0; dd < KT; dd += 2) {
            const int d = kt + dd;
            const float wm0 = W_mem[(size_t)d * DIM + i];
            const float wm1 = W_mem[(size_t)(d + 1) * DIM + i];
            const float4 c4  = WT[dd >> 1][il];                      // lane read, contiguous
            const float4 mu0 = *(const float4*)&MU[slot][dd];        // broadcast (m,u,m',u')
            const float4 mu1 = *(const float4*)&MU[slot + 4][dd];    // broadcast
            am0 = fmaf(mu0.x, wm0, am0);  am0 = fmaf(mu0.z, wm1, am0);
            a10 = fmaf(mu0.y, c4.x, a10); a10 = fmaf(mu0.w, c4.z, a10);
            a20 = fmaf(mu0.y, c4.y, a20); a20 = fmaf(mu0.w, c4.w, a20);
            am1 = fmaf(mu1.x, wm0, am1);  am1 = fmaf(mu1.z, wm1, am1);
            a11 = fmaf(mu1.y, c4.x, a11); a11 = fmaf(mu1.w, c4.z, a11);
            a21 = fmaf(mu1.y, c4.y, a21); a21 = fmaf(mu1.w, c4.w, a21);
        }
    }

    const float bm = b_mem[i];
    w_out[(size_t)(b0 + slot)     * DIM + i] = (am0 + bm) * a10 + a20;
    w_out[(size_t)(b0 + slot + 4) * DIM + i] = (am1 + bm) * a11 + a21;
}

// ---------------------------------------------------------------------------
// Kernel 2: per-b streaming pass over know (float4, 16 waves/CU).
//   logits[n] = sum_d know[b,d,n]*w[b,d];  ksum[n] = sum_d know[b,d,n]
//   out[b,n]  = softmax_n(logits)[n] * ksum[n]
// grid BB blocks x (64,16). Wave ty owns d-slab [32*ty, 32*ty+32);
// lanes tx<49 each own one float4 n-group (196 = 49*4).
// ---------------------------------------------------------------------------
__global__ __launch_bounds__(1024) void read_kernel(
    const float* __restrict__ know,  // (BB, DIM, NN)
    const float* __restrict__ w,     // (BB, DIM)
    float* __restrict__ out)         // (BB, NN)
{
    __shared__ float  w_s[DIM];
    __shared__ float4 part_lg[16][50];
    __shared__ float4 part_ks[16][50];
    __shared__ float  tmp[256];
    __shared__ float  bc[2];

    const int tx  = threadIdx.x;       // 0..63 (lane)
    const int ty  = threadIdx.y;       // 0..15 (wave)
    const int tid = ty * 64 + tx;
    const int b   = blockIdx.x;

    if (tid < DIM) w_s[tid] = w[(size_t)b * DIM + tid];
    __syncthreads();

    float4 lg = make_float4(0.f, 0.f, 0.f, 0.f);
    float4 ks = make_float4(0.f, 0.f, 0.f, 0.f);
    if (tx < 49) {
        const float4* kp = (const float4*)(know + (size_t)b * DIM * NN) + (size_t)(ty * 32) * 49 + tx;
        const float*  wp = w_s + ty * 32;
        #pragma unroll 8
        for (int dd = 0; dd < 32; ++dd) {
            const float4 kv = kp[(size_t)dd * 49];
            const float  wv = wp[dd];
            lg.x = fmaf(kv.x, wv, lg.x); lg.y = fmaf(kv.y, wv, lg.y);
            lg.z = fmaf(kv.z, wv, lg.z); lg.w = fmaf(kv.w, wv, lg.w);
            ks.x += kv.x; ks.y += kv.y; ks.z += kv.z; ks.w += kv.w;
        }
        part_lg[ty][tx] = lg;
        part_ks[ty][tx] = ks;
    }
    __syncthreads();

    // combine 16 wave-partials: thread n (<196) sums its scalar slot
    float lgn = 0.f, ksn = 0.f;
    if (tid < NN) {
        const int ng = tid >> 2, j = tid & 3;
        #pragma unroll
        for (int t = 0; t < 16; ++t) {
            lgn += ((const float*)&part_lg[t][ng])[j];
            ksn += ((const float*)&part_ks[t][ng])[j];
        }
    }

    // block max over 196 logits
    if (tid < 256) tmp[tid] = (tid < NN) ? lgn : -FLT_MAX;
    __syncthreads();
    if (tid < 64) {
        float m = fmaxf(fmaxf(tmp[tid], tmp[tid + 64]),
                        fmaxf(tmp[tid + 128], tmp[tid + 192]));
        #pragma unroll
        for (int o = 32; o; o >>= 1) m = fmaxf(m, __shfl_down(m, o));
        if (tid == 0) bc[0] = m;
    }
    __syncthreads();

    const float e = (tid < NN) ? __expf(lgn - bc[0]) : 0.f;
    if (tid < 256) tmp[tid] = e;
    __syncthreads();
    if (tid < 64) {
        float s = tmp[tid] + tmp[tid + 64] + tmp[tid + 128] + tmp[tid + 192];
        #pragma unroll
        for (int o = 32; o; o >>= 1) s += __shfl_down(s, o);
        if (tid == 0) bc[1] = s;
    }
    __syncthreads();

    if (tid < NN) out[(size_t)b * NN + tid] = e / bc[1] * ksn;
}

// ---------------------------------------------------------------------------
extern "C" void kernel_launch(void* const* d_in, const int* in_sizes, int n_in,
                              void* d_out, int out_size, void* d_ws, size_t ws_size,
                              hipStream_t stream) {
    const float* memory   = (const float*)d_in[0];
    const float* know     = (const float*)d_in[1];
    const float* control  = (const float*)d_in[2];
    const float* W_mem    = (const float*)d_in[3];
    const float* b_mem    = (const float*)d_in[4];
    const float* W_concat = (const float*)d_in[5];
    // d_in[6] = b_concat : uniform over n -> softmax-invariant, unused
    const float* W_attn   = (const float*)d_in[7];
    // d_in[8] = b_attn   : same, unused
    float* w_ws = (float*)d_ws;          // (BB, DIM) = 512 KB scratch
    float* outp = (float*)d_out;         // (BB, NN) f32

    dim3 g1(BB / TB, DIM / 64);          // (32, 8)
    prep_kernel<<<g1, dim3(256), 0, stream>>>(memory, control, W_mem, b_mem,
                                              W_concat, W_attn, w_ws);
    read_kernel<<<dim3(BB), dim3(64, 16), 0, stream>>>(know, w_ws, outp);
}

// Round 3
// 50.334 us; speedup vs baseline: 1.8901x; 1.8901x over previous
//
#include <hip/hip_runtime.h>
#include <cfloat>

// Problem dims (fixed by reference)
#define BB   256   // batch
#define DIM  512
#define NN   196
#define TB   8     // b-tile in prep kernel

// ---------------------------------------------------------------------------
// Kernel 1: prep — w[b,i] = (mem[b,i] + b_mem[i]) * v1[b,i] + v2[b,i]
//   mem[b,i] = sum_d memory[-1][b,d] * W_mem[d,i]
//   v1[b,i]  = sum_d u[b,d] * W_concat[i,     d]   (u = control[-1]*W_attn)
//   v2[b,i]  = sum_d u[b,d] * W_concat[DIM+i, d]
//
// grid (BB/TB, DIM/64) = (32, 8); block (64,16) = 16 waves = 4 waves/SIMD.
// k=512 is split across the 16 waves (8-wide chunk per wave per pass,
// 4 passes), so global-load latency is hidden by TLP; per-wave partials
// are tree-combined in LDS at the end. LDS 104 KB -> 1 block/CU, 16 waves.
// ---------------------------------------------------------------------------
__global__ __launch_bounds__(1024) void prep_kernel(
    const float* __restrict__ memory,    // (2,BB,DIM)
    const float* __restrict__ control,   // (2,BB,DIM)
    const float* __restrict__ W_mem,     // (DIM,DIM) row-major [d][i]
    const float* __restrict__ b_mem,     // (DIM)
    const float* __restrict__ W_concat,  // (2*DIM, DIM) row-major [c][j]
    const float* __restrict__ W_attn,    // (DIM,1)
    float* __restrict__ w_out)           // (BB, DIM)
{
    // smem union: passes use WT = float2[16 waves][8 k][64 i] (16384 floats);
    // epilogue reuses it as P = float[3 acc][8 b][16 ty][64 i] (24576 floats).
    __shared__ float  smem[24576];       // 96 KB
    __shared__ float4 MU4[4][128];       // 8 KB: (m[b],u[b],m[b+4],u[b+4]) per k

    const int tx  = threadIdx.x;   // 0..63 lane (= i within tile)
    const int ty  = threadIdx.y;   // 0..15 wave (= k-chunk owner)
    const int tid = ty * 64 + tx;
    const int b0 = blockIdx.x * TB;
    const int i0 = blockIdx.y * 64;

    const float* mem_in = memory  + (size_t)BB * DIM;  // memory[-1]
    const float* ctl_in = control + (size_t)BB * DIM;  // control[-1]

    float am[8] = {0,0,0,0,0,0,0,0};
    float a1[8] = {0,0,0,0,0,0,0,0};
    float a2[8] = {0,0,0,0,0,0,0,0};

    float2* WT = (float2*)smem;
    const int r8 = tx >> 1;          // 0..31 (row within 32-row stripe)
    const int sc = (tx & 1) * 4;     // float4 col group within 8-wide chunk

    for (int kp = 0; kp < 4; ++kp) {
        __syncthreads();  // previous pass's compute done (WT reusable)

        // stage MU4: 4 b-pairs x 128 k, one float4 per thread (tid < 512)
        if (tid < 512) {
            const int bp = tid >> 7;          // 0..3
            const int kl = tid & 127;
            const int d  = kp * 128 + kl;
            const float wa = W_attn[d];
            MU4[bp][kl] = make_float4(
                mem_in[(size_t)(b0 + bp)     * DIM + d],
                ctl_in[(size_t)(b0 + bp)     * DIM + d] * wa,
                mem_in[(size_t)(b0 + bp + 4) * DIM + d],
                ctl_in[(size_t)(b0 + bp + 4) * DIM + d] * wa);
        }

        // wave ty stages its own [8 k][64 i] (c1,c2) tile, transposed
        const int kc = kp * 128 + ty * 8;     // global k base of this wave
        #pragma unroll
        for (int rr = 0; rr < 64; rr += 32) {
            const int row = rr + r8;
            const float4 q1 = *(const float4*)&W_concat[(size_t)(i0 + row)       * DIM + kc + sc];
            const float4 q2 = *(const float4*)&W_concat[(size_t)(DIM + i0 + row) * DIM + kc + sc];
            WT[(ty * 8 + sc + 0) * 64 + row] = make_float2(q1.x, q2.x);
            WT[(ty * 8 + sc + 1) * 64 + row] = make_float2(q1.y, q2.y);
            WT[(ty * 8 + sc + 2) * 64 + row] = make_float2(q1.z, q2.z);
            WT[(ty * 8 + sc + 3) * 64 + row] = make_float2(q1.w, q2.w);
        }
        __syncthreads();

        // compute: 8 k-steps, all data LDS/L2-hot, 24 FMA per step
        #pragma unroll
        for (int kk = 0; kk < 8; ++kk) {
            const int d  = kc + kk;
            const int kl = ty * 8 + kk;
            const float  wm = W_mem[(size_t)d * DIM + i0 + tx];  // coalesced
            const float2 c  = WT[(ty * 8 + kk) * 64 + tx];       // lane b64
            #pragma unroll
            for (int bp = 0; bp < 4; ++bp) {
                const float4 mu = MU4[bp][kl];                   // broadcast b128
                am[bp]     = fmaf(mu.x, wm,  am[bp]);
                a1[bp]     = fmaf(mu.y, c.x, a1[bp]);
                a2[bp]     = fmaf(mu.y, c.y, a2[bp]);
                am[bp + 4] = fmaf(mu.z, wm,  am[bp + 4]);
                a1[bp + 4] = fmaf(mu.w, c.x, a1[bp + 4]);
                a2[bp + 4] = fmaf(mu.w, c.y, a2[bp + 4]);
            }
        }
    }

    __syncthreads();
    // write per-wave partials: P[acc][b][ty][i]
    #pragma unroll
    for (int b = 0; b < 8; ++b) {
        smem[((0 * 8 + b) * 16 + ty) * 64 + tx] = am[b];
        smem[((1 * 8 + b) * 16 + ty) * 64 + tx] = a1[b];
        smem[((2 * 8 + b) * 16 + ty) * 64 + tx] = a2[b];
    }
    __syncthreads();

    // combine 16 wave-partials and apply the nonlinearity
    if (tid < 512) {
        const int b = tid >> 6, il = tid & 63;
        float sm = 0.f, s1 = 0.f, s2 = 0.f;
        #pragma unroll
        for (int t = 0; t < 16; ++t) {
            sm += smem[((0 * 8 + b) * 16 + t) * 64 + il];
            s1 += smem[((1 * 8 + b) * 16 + t) * 64 + il];
            s2 += smem[((2 * 8 + b) * 16 + t) * 64 + il];
        }
        w_out[(size_t)(b0 + b) * DIM + i0 + il] = (sm + b_mem[i0 + il]) * s1 + s2;
    }
}

// ---------------------------------------------------------------------------
// Kernel 2: per-b streaming pass over know (float4, 16 waves/block).
//   logits[n] = sum_d know[b,d,n]*w[b,d];  ksum[n] = sum_d know[b,d,n]
//   out[b,n]  = softmax_n(logits)[n] * ksum[n]
// grid BB blocks x (64,16). Wave ty owns d-slab [32*ty, 32*ty+32);
// lanes tx<49 each own one float4 n-group (196 = 49*4).
// ---------------------------------------------------------------------------
__global__ __launch_bounds__(1024) void read_kernel(
    const float* __restrict__ know,  // (BB, DIM, NN)
    const float* __restrict__ w,     // (BB, DIM)
    float* __restrict__ out)         // (BB, NN)
{
    __shared__ float  w_s[DIM];
    __shared__ float4 part_lg[16][50];
    __shared__ float4 part_ks[16][50];
    __shared__ float  tmp[256];
    __shared__ float  bc[2];

    const int tx  = threadIdx.x;       // 0..63 (lane)
    const int ty  = threadIdx.y;       // 0..15 (wave)
    const int tid = ty * 64 + tx;
    const int b   = blockIdx.x;

    if (tid < DIM) w_s[tid] = w[(size_t)b * DIM + tid];
    __syncthreads();

    float4 lg = make_float4(0.f, 0.f, 0.f, 0.f);
    float4 ks = make_float4(0.f, 0.f, 0.f, 0.f);
    if (tx < 49) {
        const float4* kp = (const float4*)(know + (size_t)b * DIM * NN) + (size_t)(ty * 32) * 49 + tx;
        const float*  wp = w_s + ty * 32;
        #pragma unroll 8
        for (int dd = 0; dd < 32; ++dd) {
            const float4 kv = kp[(size_t)dd * 49];
            const float  wv = wp[dd];
            lg.x = fmaf(kv.x, wv, lg.x); lg.y = fmaf(kv.y, wv, lg.y);
            lg.z = fmaf(kv.z, wv, lg.z); lg.w = fmaf(kv.w, wv, lg.w);
            ks.x += kv.x; ks.y += kv.y; ks.z += kv.z; ks.w += kv.w;
        }
        part_lg[ty][tx] = lg;
        part_ks[ty][tx] = ks;
    }
    __syncthreads();

    // combine 16 wave-partials: thread n (<196) sums its scalar slot
    float lgn = 0.f, ksn = 0.f;
    if (tid < NN) {
        const int ng = tid >> 2, j = tid & 3;
        #pragma unroll
        for (int t = 0; t < 16; ++t) {
            lgn += ((const float*)&part_lg[t][ng])[j];
            ksn += ((const float*)&part_ks[t][ng])[j];
        }
    }

    // block max over 196 logits
    if (tid < 256) tmp[tid] = (tid < NN) ? lgn : -FLT_MAX;
    __syncthreads();
    if (tid < 64) {
        float m = fmaxf(fmaxf(tmp[tid], tmp[tid + 64]),
                        fmaxf(tmp[tid + 128], tmp[tid + 192]));
        #pragma unroll
        for (int o = 32; o; o >>= 1) m = fmaxf(m, __shfl_down(m, o));
        if (tid == 0) bc[0] = m;
    }
    __syncthreads();

    const float e = (tid < NN) ? __expf(lgn - bc[0]) : 0.f;
    if (tid < 256) tmp[tid] = e;
    __syncthreads();
    if (tid < 64) {
        float s = tmp[tid] + tmp[tid + 64] + tmp[tid + 128] + tmp[tid + 192];
        #pragma unroll
        for (int o = 32; o; o >>= 1) s += __shfl_down(s, o);
        if (tid == 0) bc[1] = s;
    }
    __syncthreads();

    if (tid < NN) out[(size_t)b * NN + tid] = e / bc[1] * ksn;
}

// ---------------------------------------------------------------------------
extern "C" void kernel_launch(void* const* d_in, const int* in_sizes, int n_in,
                              void* d_out, int out_size, void* d_ws, size_t ws_size,
                              hipStream_t stream) {
    const float* memory   = (const float*)d_in[0];
    const float* know     = (const float*)d_in[1];
    const float* control  = (const float*)d_in[2];
    const float* W_mem    = (const float*)d_in[3];
    const float* b_mem    = (const float*)d_in[4];
    const float* W_concat = (const float*)d_in[5];
    // d_in[6] = b_concat : uniform over n -> softmax-invariant, unused
    const float* W_attn   = (const float*)d_in[7];
    // d_in[8] = b_attn   : same, unused
    float* w_ws = (float*)d_ws;          // (BB, DIM) = 512 KB scratch
    float* outp = (float*)d_out;         // (BB, NN) f32

    prep_kernel<<<dim3(BB / TB, DIM / 64), dim3(64, 16), 0, stream>>>(
        memory, control, W_mem, b_mem, W_concat, W_attn, w_ws);
    read_kernel<<<dim3(BB), dim3(64, 16), 0, stream>>>(know, w_ws, outp);
}

// Round 4
// 39.732 us; speedup vs baseline: 2.3944x; 1.2668x over previous
//
#include <hip/hip_runtime.h>
#include <cfloat>

// Problem dims (fixed by reference)
#define BB   256   // batch
#define DIM  512
#define NN   196
#define BT   4     // b-tile in prep kernel
#define IT   32    // i-tile in prep kernel

// ---------------------------------------------------------------------------
// Kernel 1: prep — w[b,i] = (mem[b,i] + b_mem[i]) * v1[b,i] + v2[b,i]
//   mem[b,i] = sum_d memory[-1][b,d] * W_mem[d,i]
//   v1[b,i]  = sum_d u[b,d] * W_concat[i,     d]   (u = control[-1]*W_attn)
//   v2[b,i]  = sum_d u[b,d] * W_concat[DIM+i, d]
//
// grid (BB/BT, DIM/IT) = (64,16) = 1024 blocks x 256 thr -> 4 blocks/CU,
// 16 waves/CU (latency overlap across blocks; barriers not exposed).
// Thread (kg = tid>>5, il = tid&31): k-slice [kg*8, kg*8+8) of each 64-k
// chunk, one i, all 4 b -> 12 accumulators. Per-wave partials combined in
// LDS at the end. LDS ~34 KB.
// ---------------------------------------------------------------------------
__global__ __launch_bounds__(256, 4) void prep_kernel(
    const float* __restrict__ memory,    // (2,BB,DIM)
    const float* __restrict__ control,   // (2,BB,DIM)
    const float* __restrict__ W_mem,     // (DIM,DIM) row-major [d][i]
    const float* __restrict__ b_mem,     // (DIM)
    const float* __restrict__ W_concat,  // (2*DIM, DIM) row-major [c][j]
    const float* __restrict__ W_attn,    // (DIM,1)
    float* __restrict__ w_out)           // (BB, DIM)
{
    __shared__ float4 MU[DIM * 2];   // 16 KB: [k*2+0]=(m0,u0,m1,u1) [k*2+1]=(m2,u2,m3,u3)
    __shared__ float  WTb[4224];     // 16.5 KB: float2[64 k][33 pad] ; epilogue: P[3072]

    const int tid = threadIdx.x;
    const int il  = tid & 31;        // i within tile
    const int kg  = tid >> 5;        // 0..7 k-group
    const int b0  = blockIdx.x * BT;
    const int i0  = blockIdx.y * IT;

    const float* mem_in = memory  + (size_t)BB * DIM;  // memory[-1]
    const float* ctl_in = control + (size_t)BB * DIM;  // control[-1]

    // ---- stage MU (once): 1024 float4 by 256 threads, coalesced over k ----
    #pragma unroll
    for (int p = 0; p < 4; ++p) {
        const int idx  = p * 256 + tid;       // 0..1023
        const int pair = idx >> 9;            // 0..1
        const int k    = idx & 511;
        const int bb   = b0 + pair * 2;
        const float wa = W_attn[k];
        MU[k * 2 + pair] = make_float4(
            mem_in[(size_t)bb       * DIM + k],
            ctl_in[(size_t)bb       * DIM + k] * wa,
            mem_in[(size_t)(bb + 1) * DIM + k],
            ctl_in[(size_t)(bb + 1) * DIM + k] * wa);
    }

    float am0 = 0.f, am1 = 0.f, am2 = 0.f, am3 = 0.f;
    float a10 = 0.f, a11 = 0.f, a12 = 0.f, a13 = 0.f;
    float a20 = 0.f, a21 = 0.f, a22 = 0.f, a23 = 0.f;

    float2* WT = (float2*)WTb;
    const int sr = tid >> 3;         // 0..31 (i row for staging)
    const int sc = tid & 7;          // 0..7  (8-col group for staging)

    for (int kt = 0; kt < DIM; kt += 64) {
        __syncthreads();   // prev chunk's compute done (covers MU on iter 0)

        // stage WT chunk: (c1,c2) for k in [kt,kt+64), i in [i0,i0+32)
        {
            const float* w1p = &W_concat[(size_t)(i0 + sr) * DIM + kt + sc * 8];
            const float* w2p = w1p + (size_t)DIM * DIM;
            const float4 q1a = *(const float4*)w1p;
            const float4 q1b = *(const float4*)(w1p + 4);
            const float4 q2a = *(const float4*)w2p;
            const float4 q2b = *(const float4*)(w2p + 4);
            const int kb = sc * 8;
            WT[(kb + 0) * 33 + sr] = make_float2(q1a.x, q2a.x);
            WT[(kb + 1) * 33 + sr] = make_float2(q1a.y, q2a.y);
            WT[(kb + 2) * 33 + sr] = make_float2(q1a.z, q2a.z);
            WT[(kb + 3) * 33 + sr] = make_float2(q1a.w, q2a.w);
            WT[(kb + 4) * 33 + sr] = make_float2(q1b.x, q2b.x);
            WT[(kb + 5) * 33 + sr] = make_float2(q1b.y, q2b.y);
            WT[(kb + 6) * 33 + sr] = make_float2(q1b.z, q2b.z);
            WT[(kb + 7) * 33 + sr] = make_float2(q1b.w, q2b.w);
        }
        __syncthreads();

        // compute this thread's 8-k slice
        #pragma unroll
        for (int kk = 0; kk < 8; ++kk) {
            const int kl = kg * 8 + kk;
            const int k  = kt + kl;
            const float  wm   = W_mem[(size_t)k * DIM + i0 + il];  // 2x128B/wave, L2
            const float2 c    = WT[kl * 33 + il];                  // lane b64
            const float4 mu01 = MU[k * 2 + 0];                     // 2-addr bcast
            const float4 mu23 = MU[k * 2 + 1];
            am0 = fmaf(mu01.x, wm,  am0);
            a10 = fmaf(mu01.y, c.x, a10);
            a20 = fmaf(mu01.y, c.y, a20);
            am1 = fmaf(mu01.z, wm,  am1);
            a11 = fmaf(mu01.w, c.x, a11);
            a21 = fmaf(mu01.w, c.y, a21);
            am2 = fmaf(mu23.x, wm,  am2);
            a12 = fmaf(mu23.y, c.x, a12);
            a22 = fmaf(mu23.y, c.y, a22);
            am3 = fmaf(mu23.z, wm,  am3);
            a13 = fmaf(mu23.w, c.x, a13);
            a23 = fmaf(mu23.w, c.y, a23);
        }
    }

    // ---- combine 8 k-group partials in LDS ----
    __syncthreads();
    // P[((kg*4 + b)*3 + acc)*32 + il]
    {
        float* P = WTb;
        const int base = kg * 4;
        P[((base + 0) * 3 + 0) * 32 + il] = am0;
        P[((base + 0) * 3 + 1) * 32 + il] = a10;
        P[((base + 0) * 3 + 2) * 32 + il] = a20;
        P[((base + 1) * 3 + 0) * 32 + il] = am1;
        P[((base + 1) * 3 + 1) * 32 + il] = a11;
        P[((base + 1) * 3 + 2) * 32 + il] = a21;
        P[((base + 2) * 3 + 0) * 32 + il] = am2;
        P[((base + 2) * 3 + 1) * 32 + il] = a12;
        P[((base + 2) * 3 + 2) * 32 + il] = a22;
        P[((base + 3) * 3 + 0) * 32 + il] = am3;
        P[((base + 3) * 3 + 1) * 32 + il] = a13;
        P[((base + 3) * 3 + 2) * 32 + il] = a23;
    }
    __syncthreads();
    if (tid < 128) {
        const float* P = WTb;
        const int b = tid >> 5, ii = tid & 31;
        float sm = 0.f, s1 = 0.f, s2 = 0.f;
        #pragma unroll
        for (int t = 0; t < 8; ++t) {
            sm += P[((t * 4 + b) * 3 + 0) * 32 + ii];
            s1 += P[((t * 4 + b) * 3 + 1) * 32 + ii];
            s2 += P[((t * 4 + b) * 3 + 2) * 32 + ii];
        }
        w_out[(size_t)(b0 + b) * DIM + i0 + ii] = (sm + b_mem[i0 + ii]) * s1 + s2;
    }
}

// ---------------------------------------------------------------------------
// Kernel 2: per-b streaming pass over know (float4, 16 waves/block).
//   logits[n] = sum_d know[b,d,n]*w[b,d];  ksum[n] = sum_d know[b,d,n]
//   out[b,n]  = softmax_n(logits)[n] * ksum[n]
// grid BB blocks x (64,16). Wave ty owns d-slab [32*ty, 32*ty+32);
// lanes tx<49 each own one float4 n-group (196 = 49*4).
// ---------------------------------------------------------------------------
__global__ __launch_bounds__(1024) void read_kernel(
    const float* __restrict__ know,  // (BB, DIM, NN)
    const float* __restrict__ w,     // (BB, DIM)
    float* __restrict__ out)         // (BB, NN)
{
    __shared__ float  w_s[DIM];
    __shared__ float4 part_lg[16][50];
    __shared__ float4 part_ks[16][50];
    __shared__ float  tmp[256];
    __shared__ float  bc[2];

    const int tx  = threadIdx.x;       // 0..63 (lane)
    const int ty  = threadIdx.y;       // 0..15 (wave)
    const int tid = ty * 64 + tx;
    const int b   = blockIdx.x;

    if (tid < DIM) w_s[tid] = w[(size_t)b * DIM + tid];
    __syncthreads();

    float4 lg = make_float4(0.f, 0.f, 0.f, 0.f);
    float4 ks = make_float4(0.f, 0.f, 0.f, 0.f);
    if (tx < 49) {
        const float4* kp = (const float4*)(know + (size_t)b * DIM * NN) + (size_t)(ty * 32) * 49 + tx;
        const float*  wp = w_s + ty * 32;
        #pragma unroll 8
        for (int dd = 0; dd < 32; ++dd) {
            const float4 kv = kp[(size_t)dd * 49];
            const float  wv = wp[dd];
            lg.x = fmaf(kv.x, wv, lg.x); lg.y = fmaf(kv.y, wv, lg.y);
            lg.z = fmaf(kv.z, wv, lg.z); lg.w = fmaf(kv.w, wv, lg.w);
            ks.x += kv.x; ks.y += kv.y; ks.z += kv.z; ks.w += kv.w;
        }
        part_lg[ty][tx] = lg;
        part_ks[ty][tx] = ks;
    }
    __syncthreads();

    // combine 16 wave-partials: thread n (<196) sums its scalar slot
    float lgn = 0.f, ksn = 0.f;
    if (tid < NN) {
        const int ng = tid >> 2, j = tid & 3;
        #pragma unroll
        for (int t = 0; t < 16; ++t) {
            lgn += ((const float*)&part_lg[t][ng])[j];
            ksn += ((const float*)&part_ks[t][ng])[j];
        }
    }

    // block max over 196 logits
    if (tid < 256) tmp[tid] = (tid < NN) ? lgn : -FLT_MAX;
    __syncthreads();
    if (tid < 64) {
        float m = fmaxf(fmaxf(tmp[tid], tmp[tid + 64]),
                        fmaxf(tmp[tid + 128], tmp[tid + 192]));
        #pragma unroll
        for (int o = 32; o; o >>= 1) m = fmaxf(m, __shfl_down(m, o));
        if (tid == 0) bc[0] = m;
    }
    __syncthreads();

    const float e = (tid < NN) ? __expf(lgn - bc[0]) : 0.f;
    if (tid < 256) tmp[tid] = e;
    __syncthreads();
    if (tid < 64) {
        float s = tmp[tid] + tmp[tid + 64] + tmp[tid + 128] + tmp[tid + 192];
        #pragma unroll
        for (int o = 32; o; o >>= 1) s += __shfl_down(s, o);
        if (tid == 0) bc[1] = s;
    }
    __syncthreads();

    if (tid < NN) out[(size_t)b * NN + tid] = e / bc[1] * ksn;
}

// ---------------------------------------------------------------------------
extern "C" void kernel_launch(void* const* d_in, const int* in_sizes, int n_in,
                              void* d_out, int out_size, void* d_ws, size_t ws_size,
                              hipStream_t stream) {
    const float* memory   = (const float*)d_in[0];
    const float* know     = (const float*)d_in[1];
    const float* control  = (const float*)d_in[2];
    const float* W_mem    = (const float*)d_in[3];
    const float* b_mem    = (const float*)d_in[4];
    const float* W_concat = (const float*)d_in[5];
    // d_in[6] = b_concat : uniform over n -> softmax-invariant, unused
    const float* W_attn   = (const float*)d_in[7];
    // d_in[8] = b_attn   : same, unused
    float* w_ws = (float*)d_ws;          // (BB, DIM) = 512 KB scratch
    float* outp = (float*)d_out;         // (BB, NN) f32

    prep_kernel<<<dim3(BB / BT, DIM / IT), dim3(256), 0, stream>>>(
        memory, control, W_mem, b_mem, W_concat, W_attn, w_ws);
    read_kernel<<<dim3(BB), dim3(64, 16), 0, stream>>>(know, w_ws, outp);
}